// Round 5
// baseline (793.039 us; speedup 1.0000x reference)
//
#include <hip/hip_runtime.h>
#include <hip/hip_bf16.h>
#include <hip/hip_fp16.h>
#include <stdint.h>

typedef float    f32x4 __attribute__((ext_vector_type(4)));
typedef float    fvec4 __attribute__((ext_vector_type(4)));
typedef _Float16 f16x8 __attribute__((ext_vector_type(8)));

#define D_MODEL 1024
#define D_FF    4096
#define NTOK    8192
#define CAP_ROWS 16896  // 132 * 128
#define NRB      132    // row blocks of 128

// ---- workspace layout (bytes) ----
#define OFF_W1  0UL           // 4*4096*1024*2 (W1^T fp16: [e][n][k])
#define OFF_W2  33554432UL    // 4*1024*4096*2 (W2^T fp16: [e][d][f])
#define OFF_XG  67108864UL    // 16896*1024*2
#define OFF_H   101711872UL   // 16896*4096*2
#define OFF_CNT 240123904UL
#define OFF_CUR 240123920UL
#define OFF_OFS 240123936UL
#define OFF_TOK 240124160UL
#define OFF_WGT 240191744UL
#define OFF_E12 240259328UL
#define OFF_W12 240292096UL
#define WS_NEED 240357632UL

__device__ __forceinline__ void gload_lds16(const void* g, void* l) {
  __builtin_amdgcn_global_load_lds(
      (const __attribute__((address_space(1))) unsigned int*)g,
      (__attribute__((address_space(3))) unsigned int*)l, 16, 0, 0);
}

// fast tanh-approx GELU: gelu(v) = v - v * rcp(1 + 2^(v*(a + b*v^2)))
// a = 0.7978845608*2*log2(e) = 2.302118131, b = a*0.044715 = 0.10293924
// inf-safe: t=inf -> rcp(1+t)=0 -> gelu=v; t->0 -> gelu->0. Max err ~3e-4.
__device__ __forceinline__ float fast_gelu(float v) {
  float v2 = v * v;
  float y2 = v * (2.302118131f + 0.10293924f * v2);
  float t = exp2f(y2);                       // native v_exp_f32
  return v - v * __builtin_amdgcn_rcpf(1.f + t);
}

// ---------------- router ----------------
__global__ __launch_bounds__(256) void router_k(
    const float* __restrict__ x, const float* __restrict__ Wr,
    const float* __restrict__ br, int* __restrict__ counts,
    int* __restrict__ e12, float* __restrict__ w12) {
  int wid = threadIdx.x >> 6, lane = threadIdx.x & 63;
  int t = blockIdx.x * 4 + wid;
  const float* xr = x + (size_t)t * D_MODEL;
  float a0 = 0.f, a1 = 0.f, a2 = 0.f, a3 = 0.f;
#pragma unroll
  for (int c = 0; c < 4; ++c) {
    int d0 = c * 256 + lane * 4;
    fvec4 xv = *(const fvec4*)(xr + d0);
#pragma unroll
    for (int j = 0; j < 4; ++j) {
      fvec4 wv = *(const fvec4*)(Wr + (size_t)(d0 + j) * 4);
      a0 += xv[j] * wv[0]; a1 += xv[j] * wv[1];
      a2 += xv[j] * wv[2]; a3 += xv[j] * wv[3];
    }
  }
#pragma unroll
  for (int m = 32; m; m >>= 1) {
    a0 += __shfl_xor(a0, m, 64); a1 += __shfl_xor(a1, m, 64);
    a2 += __shfl_xor(a2, m, 64); a3 += __shfl_xor(a3, m, 64);
  }
  if (lane == 0) {
    float l[4] = {a0 + br[0], a1 + br[1], a2 + br[2], a3 + br[3]};
    int e1 = 0; float m1 = l[0];
#pragma unroll
    for (int e = 1; e < 4; ++e) if (l[e] > m1) { m1 = l[e]; e1 = e; }
    int e2 = -1; float m2 = -1e30f;
#pragma unroll
    for (int e = 0; e < 4; ++e) if (e != e1 && l[e] > m2) { m2 = l[e]; e2 = e; }
    float tt = expf(m2 - m1);
    float w1 = 1.f / (1.f + tt), w2 = tt / (1.f + tt);
    atomicAdd(&counts[e1], 1); atomicAdd(&counts[e2], 1);
    e12[t] = e1 | (e2 << 8);
    w12[2 * t] = w1; w12[2 * t + 1] = w2;
  }
}

// ---------------- prefix: 128-aligned expert offsets ----------------
__global__ void prefix_k(const int* __restrict__ counts, int* __restrict__ offs,
                         int* __restrict__ cursor) {
  if (threadIdx.x == 0 && blockIdx.x == 0) {
    int o = 0;
#pragma unroll
    for (int e = 0; e < 4; ++e) {
      offs[e] = o; cursor[e] = o;
      o += (counts[e] + 127) & ~127;
    }
    offs[4] = o;
  }
}

// ---------------- scatter lists ----------------
__global__ __launch_bounds__(256) void lists_k(
    const int* __restrict__ e12, const float* __restrict__ w12,
    int* __restrict__ cursor, int* __restrict__ tok, float* __restrict__ wgt) {
  int t = blockIdx.x * 256 + threadIdx.x;
  int p = e12[t];
  int e1 = p & 255, e2 = p >> 8;
  int i1 = atomicAdd(&cursor[e1], 1); tok[i1] = t; wgt[i1] = w12[2 * t];
  int i2 = atomicAdd(&cursor[e2], 1); tok[i2] = t; wgt[i2] = w12[2 * t + 1];
}

// ---------------- gather ----------------
__global__ __launch_bounds__(128) void gather_k(
    const float* __restrict__ x, const int* __restrict__ offs,
    const int* __restrict__ counts, const int* __restrict__ tok,
    _Float16* __restrict__ Xg) {
  int b = blockIdx.x;
  if (b >= offs[4]) return;
  int e = 0;
  while (e < 3 && b >= offs[e + 1]) ++e;
  int tid = threadIdx.x;
  f16x8 o;
  if (b < offs[e] + counts[e]) {
    int t = tok[b];
    const float* src = x + (size_t)t * D_MODEL + tid * 8;
    fvec4 v0 = *(const fvec4*)src;
    fvec4 v1 = *(const fvec4*)(src + 4);
#pragma unroll
    for (int j = 0; j < 4; ++j) { o[j] = (_Float16)v0[j]; o[4 + j] = (_Float16)v1[j]; }
  } else {
#pragma unroll
    for (int j = 0; j < 8; ++j) o[j] = (_Float16)0.f;
  }
  *(f16x8*)(Xg + (size_t)b * D_MODEL + tid * 8) = o;
}

// ---------------- transpose-convert weights ----------------
__global__ __launch_bounds__(256) void wtrans_k(
    const float* __restrict__ in, _Float16* __restrict__ out, int K, int N) {
  __shared__ float tile[64][65];
  int e = blockIdx.z;
  int n0 = blockIdx.x * 64, k0 = blockIdx.y * 64;
  const float* src = in + (size_t)e * K * N;
  _Float16* dst = out + (size_t)e * K * N;
  int t = threadIdx.x;
  {
    int kk = t >> 2, nc = (t & 3) * 16;
    const float* p = src + (size_t)(k0 + kk) * N + n0 + nc;
#pragma unroll
    for (int j = 0; j < 4; ++j) {
      fvec4 v = *(const fvec4*)(p + j * 4);
      tile[kk][nc + j * 4 + 0] = v[0]; tile[kk][nc + j * 4 + 1] = v[1];
      tile[kk][nc + j * 4 + 2] = v[2]; tile[kk][nc + j * 4 + 3] = v[3];
    }
  }
  __syncthreads();
  {
    int nn = t >> 2, kb = (t & 3) * 16;
    f16x8 o0, o1;
#pragma unroll
    for (int j = 0; j < 8; ++j) o0[j] = (_Float16)tile[kb + j][nn];
#pragma unroll
    for (int j = 0; j < 8; ++j) o1[j] = (_Float16)tile[kb + 8 + j][nn];
    _Float16* q = dst + (size_t)(n0 + nn) * K + k0 + kb;
    *(f16x8*)q = o0;
    *((f16x8*)q + 1) = o1;
  }
}

// XOR-swizzled LDS fragment read (zero bank conflicts, proven r1)
__device__ __forceinline__ f16x8 lds_frag(const char* base, int row, int kbyte) {
  return *(const f16x8*)(base + row * 128 + (kbyte ^ ((row & 7) << 4)));
}

// ============ GEMM1: 128x256 tile, K=1024, fast-gelu epilogue ============
__global__ __launch_bounds__(256, 2) void gemm1_k(
    const _Float16* __restrict__ A, const _Float16* __restrict__ B,
    const float* __restrict__ bias, const int* __restrict__ offs,
    const int* __restrict__ counts, _Float16* __restrict__ outH) {
  __shared__ char lds[49152];
  // nwg = 132*16 = 2112; bijective XCD swizzle: q=264
  int bid = blockIdx.x;
  int wg = (bid & 7) * 264 + (bid >> 3);
  int col = wg & 15, row = wg >> 4;       // col-fastest
  int rowBase = row * 128;
  if (rowBase >= offs[4]) return;
  int e = 0;
  while (e < 3 && rowBase >= offs[e + 1]) ++e;
  if (rowBase >= offs[e] + counts[e]) return;
  int colBase = col * 256;

  int tid = threadIdx.x, wid = tid >> 6, lane = tid & 63;
  int wr = wid >> 1, wc = wid & 1;
  int ln = lane & 15;
  int srow = lane >> 3;
  int kx = (lane & 7) ^ srow;
  const _Float16* Abase = A + (size_t)rowBase * 1024 + kx * 8;
  const _Float16* Bbase = B + (size_t)e * D_FF * 1024 + (size_t)colBase * 1024 + kx * 8;
  char* ldsA = lds;
  char* ldsB = lds + 16384;

  f32x4 acc[4][8];
  f32x4 zero = {0.f, 0.f, 0.f, 0.f};
#pragma unroll
  for (int m = 0; m < 4; ++m)
#pragma unroll
    for (int n = 0; n < 8; ++n) acc[m][n] = zero;

  for (int k0 = 0; k0 < 1024; k0 += 64) {
#pragma unroll
    for (int i = 0; i < 4; ++i) {
      int chunk = wid * 4 + i;
      gload_lds16(Abase + (size_t)(chunk * 8 + srow) * 1024 + k0, ldsA + chunk * 1024);
    }
#pragma unroll
    for (int i = 0; i < 8; ++i) {
      int chunk = wid * 8 + i;
      gload_lds16(Bbase + (size_t)(chunk * 8 + srow) * 1024 + k0, ldsB + chunk * 1024);
    }
    __syncthreads();
#pragma unroll
    for (int kk = 0; kk < 2; ++kk) {
      int kbyte = kk * 64 + (lane >> 4) * 16;
      f16x8 af[4], bf[8];
#pragma unroll
      for (int m = 0; m < 4; ++m)
        af[m] = lds_frag(ldsA, wr * 64 + m * 16 + ln, kbyte);
#pragma unroll
      for (int n = 0; n < 8; ++n)
        bf[n] = lds_frag(ldsB, wc * 128 + n * 16 + ln, kbyte);
#pragma unroll
      for (int m = 0; m < 4; ++m)
#pragma unroll
        for (int n = 0; n < 8; ++n)
          acc[m][n] = __builtin_amdgcn_mfma_f32_16x16x32_f16(af[m], bf[n], acc[m][n], 0, 0, 0);
    }
    __syncthreads();
  }

  int col0 = colBase + wc * 128 + ln;
  float bv[8];
#pragma unroll
  for (int n = 0; n < 8; ++n) bv[n] = bias[(size_t)e * D_FF + col0 + n * 16];
#pragma unroll
  for (int m = 0; m < 4; ++m) {
    int rbase = rowBase + wr * 64 + m * 16 + (lane >> 4) * 4;
#pragma unroll
    for (int j = 0; j < 4; ++j) {
      size_t ro = (size_t)(rbase + j) * D_FF;
#pragma unroll
      for (int n = 0; n < 8; ++n) {
        float v = fast_gelu(acc[m][n][j] + bv[n]);
        outH[ro + col0 + n * 16] = (_Float16)v;
      }
    }
  }
}

// ============ GEMM2: 128x256 tile, K=4096, weighted-atomic epilogue ============
// A: H [CAP_ROWS][4096]; B: W2^T [4][1024][4096]; out: atomicAdd into out[tok][d].
__global__ __launch_bounds__(256, 2) void gemm2_k(
    const _Float16* __restrict__ A, const _Float16* __restrict__ B,
    const float* __restrict__ bias, const int* __restrict__ offs,
    const int* __restrict__ counts, const int* __restrict__ tok,
    const float* __restrict__ wgt, float* __restrict__ outF) {
  __shared__ char lds[49152];
  // nwg = 132*4 = 528; bijective XCD swizzle: q=66
  int bid = blockIdx.x;
  int wg = (bid & 7) * 66 + (bid >> 3);
  int col = wg & 3, row = wg >> 2;        // col-fastest: consecutive wg share H-panel
  int rowBase = row * 128;
  if (rowBase >= offs[4]) return;
  int e = 0;
  while (e < 3 && rowBase >= offs[e + 1]) ++e;
  int eoff = offs[e], cnt = counts[e];
  if (rowBase >= eoff + cnt) return;
  int colBase = col * 256;

  int tid = threadIdx.x, wid = tid >> 6, lane = tid & 63;
  int wr = wid >> 1, wc = wid & 1;
  int ln = lane & 15;
  int srow = lane >> 3;
  int kx = (lane & 7) ^ srow;
  const _Float16* Abase = A + (size_t)rowBase * 4096 + kx * 8;
  const _Float16* Bbase = B + (size_t)e * D_MODEL * 4096 + (size_t)colBase * 4096 + kx * 8;
  char* ldsA = lds;
  char* ldsB = lds + 16384;

  f32x4 acc[4][8];
  f32x4 zero = {0.f, 0.f, 0.f, 0.f};
#pragma unroll
  for (int m = 0; m < 4; ++m)
#pragma unroll
    for (int n = 0; n < 8; ++n) acc[m][n] = zero;

  for (int k0 = 0; k0 < 4096; k0 += 64) {
#pragma unroll
    for (int i = 0; i < 4; ++i) {
      int chunk = wid * 4 + i;               // A rows 0..127
      gload_lds16(Abase + (size_t)(chunk * 8 + srow) * 4096 + k0, ldsA + chunk * 1024);
    }
#pragma unroll
    for (int i = 0; i < 8; ++i) {
      int chunk = wid * 8 + i;               // B rows 0..255
      gload_lds16(Bbase + (size_t)(chunk * 8 + srow) * 4096 + k0, ldsB + chunk * 1024);
    }
    __syncthreads();
#pragma unroll
    for (int kk = 0; kk < 2; ++kk) {
      int kbyte = kk * 64 + (lane >> 4) * 16;
      f16x8 af[4], bf[8];
#pragma unroll
      for (int m = 0; m < 4; ++m)
        af[m] = lds_frag(ldsA, wr * 64 + m * 16 + ln, kbyte);
#pragma unroll
      for (int n = 0; n < 8; ++n)
        bf[n] = lds_frag(ldsB, wc * 128 + n * 16 + ln, kbyte);
#pragma unroll
      for (int m = 0; m < 4; ++m)
#pragma unroll
        for (int n = 0; n < 8; ++n)
          acc[m][n] = __builtin_amdgcn_mfma_f32_16x16x32_f16(af[m], bf[n], acc[m][n], 0, 0, 0);
    }
    __syncthreads();
  }

  int col0 = colBase + wc * 128 + ln;
  float bv[8];
#pragma unroll
  for (int n = 0; n < 8; ++n) bv[n] = bias[(size_t)e * D_MODEL + col0 + n * 16];
#pragma unroll
  for (int m = 0; m < 4; ++m) {
    int rbase = rowBase + wr * 64 + m * 16 + (lane >> 4) * 4;
#pragma unroll
    for (int j = 0; j < 4; ++j) {
      int grow = rbase + j;
      if (grow - eoff < cnt) {
        int t = tok[grow];
        float w = wgt[grow];
        size_t o = (size_t)t * D_MODEL + col0;
#pragma unroll
        for (int n = 0; n < 8; ++n)
          atomicAdd(&outF[o + n * 16], w * (acc[m][n][j] + bv[n]));
      }
    }
  }
}

extern "C" void kernel_launch(void* const* d_in, const int* in_sizes, int n_in,
                              void* d_out, int out_size, void* d_ws, size_t ws_size,
                              hipStream_t stream) {
  const float* x  = (const float*)d_in[0];
  const float* Wr = (const float*)d_in[1];
  const float* br = (const float*)d_in[2];
  const float* W1 = (const float*)d_in[3];
  const float* b1 = (const float*)d_in[4];
  const float* W2 = (const float*)d_in[5];
  const float* b2 = (const float*)d_in[6];
  float* out = (float*)d_out;
  char* ws = (char*)d_ws;
  if (ws_size < WS_NEED) return;

  _Float16* W1f = (_Float16*)(ws + OFF_W1);
  _Float16* W2f = (_Float16*)(ws + OFF_W2);
  _Float16* Xg  = (_Float16*)(ws + OFF_XG);
  _Float16* H   = (_Float16*)(ws + OFF_H);
  int*   counts = (int*)(ws + OFF_CNT);
  int*   cursor = (int*)(ws + OFF_CUR);
  int*   offs   = (int*)(ws + OFF_OFS);
  int*   tok    = (int*)(ws + OFF_TOK);
  float* wgt    = (float*)(ws + OFF_WGT);
  int*   e12    = (int*)(ws + OFF_E12);
  float* w12    = (float*)(ws + OFF_W12);

  hipMemsetAsync(counts, 0, 16, stream);
  hipMemsetAsync(d_out, 0, (size_t)out_size * sizeof(float), stream);

  router_k<<<NTOK / 4, 256, 0, stream>>>(x, Wr, br, counts, e12, w12);
  prefix_k<<<1, 64, 0, stream>>>(counts, offs, cursor);
  lists_k<<<NTOK / 256, 256, 0, stream>>>(e12, w12, cursor, tok, wgt);
  gather_k<<<CAP_ROWS, 128, 0, stream>>>(x, offs, counts, tok, Xg);
  wtrans_k<<<dim3(64, 16, 4), 256, 0, stream>>>(W1, W1f, 1024, 4096);
  wtrans_k<<<dim3(16, 64, 4), 256, 0, stream>>>(W2, W2f, 4096, 1024);

  gemm1_k<<<NRB * 16, 256, 0, stream>>>(Xg, W1f, b1, offs, counts, H);
  gemm2_k<<<NRB * 4, 256, 0, stream>>>(H, W2f, b2, offs, counts, tok, wgt, out);
}

// Round 6
// 742.976 us; speedup vs baseline: 1.0674x; 1.0674x over previous
//
#include <hip/hip_runtime.h>
#include <hip/hip_bf16.h>
#include <hip/hip_fp16.h>
#include <stdint.h>

typedef float    f32x4 __attribute__((ext_vector_type(4)));
typedef float    fvec4 __attribute__((ext_vector_type(4)));
typedef _Float16 f16x8 __attribute__((ext_vector_type(8)));

#define D_MODEL 1024
#define D_FF    4096
#define NTOK    8192
#define CAP_ROWS 16896  // 132 * 128
#define NRB      132    // row blocks of 128

// ---- workspace layout (bytes) ----
#define OFF_W1  0UL           // 4*4096*1024*2 (W1^T fp16: [e][n][k])
#define OFF_W2  33554432UL    // 4*1024*4096*2 (W2^T fp16: [e][d][f])
#define OFF_XG  67108864UL    // 16896*1024*2
#define OFF_H   101711872UL   // 16896*4096*2
#define OFF_CNT 240123904UL
#define OFF_CUR 240123920UL
#define OFF_OFS 240123936UL
#define OFF_TOK 240124160UL
#define OFF_WGT 240191744UL
#define OFF_E12 240259328UL
#define OFF_W12 240292096UL
#define WS_NEED 240357632UL

__device__ __forceinline__ void gload_lds16(const void* g, void* l) {
  __builtin_amdgcn_global_load_lds(
      (const __attribute__((address_space(1))) unsigned int*)g,
      (__attribute__((address_space(3))) unsigned int*)l, 16, 0, 0);
}

// fast tanh-approx GELU (inf-safe), max err ~3e-4
__device__ __forceinline__ float fast_gelu(float v) {
  float v2 = v * v;
  float y2 = v * (2.302118131f + 0.10293924f * v2);
  float t = exp2f(y2);
  return v - v * __builtin_amdgcn_rcpf(1.f + t);
}

// ---------------- router ----------------
__global__ __launch_bounds__(256) void router_k(
    const float* __restrict__ x, const float* __restrict__ Wr,
    const float* __restrict__ br, int* __restrict__ counts,
    int* __restrict__ e12, float* __restrict__ w12) {
  int wid = threadIdx.x >> 6, lane = threadIdx.x & 63;
  int t = blockIdx.x * 4 + wid;
  const float* xr = x + (size_t)t * D_MODEL;
  float a0 = 0.f, a1 = 0.f, a2 = 0.f, a3 = 0.f;
#pragma unroll
  for (int c = 0; c < 4; ++c) {
    int d0 = c * 256 + lane * 4;
    fvec4 xv = *(const fvec4*)(xr + d0);
#pragma unroll
    for (int j = 0; j < 4; ++j) {
      fvec4 wv = *(const fvec4*)(Wr + (size_t)(d0 + j) * 4);
      a0 += xv[j] * wv[0]; a1 += xv[j] * wv[1];
      a2 += xv[j] * wv[2]; a3 += xv[j] * wv[3];
    }
  }
#pragma unroll
  for (int m = 32; m; m >>= 1) {
    a0 += __shfl_xor(a0, m, 64); a1 += __shfl_xor(a1, m, 64);
    a2 += __shfl_xor(a2, m, 64); a3 += __shfl_xor(a3, m, 64);
  }
  if (lane == 0) {
    float l[4] = {a0 + br[0], a1 + br[1], a2 + br[2], a3 + br[3]};
    int e1 = 0; float m1 = l[0];
#pragma unroll
    for (int e = 1; e < 4; ++e) if (l[e] > m1) { m1 = l[e]; e1 = e; }
    int e2 = -1; float m2 = -1e30f;
#pragma unroll
    for (int e = 0; e < 4; ++e) if (e != e1 && l[e] > m2) { m2 = l[e]; e2 = e; }
    float tt = expf(m2 - m1);
    float w1 = 1.f / (1.f + tt), w2 = tt / (1.f + tt);
    atomicAdd(&counts[e1], 1); atomicAdd(&counts[e2], 1);
    e12[t] = e1 | (e2 << 8);
    w12[2 * t] = w1; w12[2 * t + 1] = w2;
  }
}

// ---------------- prefix: 128-aligned expert offsets ----------------
__global__ void prefix_k(const int* __restrict__ counts, int* __restrict__ offs,
                         int* __restrict__ cursor) {
  if (threadIdx.x == 0 && blockIdx.x == 0) {
    int o = 0;
#pragma unroll
    for (int e = 0; e < 4; ++e) {
      offs[e] = o; cursor[e] = o;
      o += (counts[e] + 127) & ~127;
    }
    offs[4] = o;
  }
}

// ---------------- scatter lists ----------------
__global__ __launch_bounds__(256) void lists_k(
    const int* __restrict__ e12, const float* __restrict__ w12,
    int* __restrict__ cursor, int* __restrict__ tok, float* __restrict__ wgt) {
  int t = blockIdx.x * 256 + threadIdx.x;
  int p = e12[t];
  int e1 = p & 255, e2 = p >> 8;
  int i1 = atomicAdd(&cursor[e1], 1); tok[i1] = t; wgt[i1] = w12[2 * t];
  int i2 = atomicAdd(&cursor[e2], 1); tok[i2] = t; wgt[i2] = w12[2 * t + 1];
}

// ---------------- fused aux: gather + wtrans(W1) + wtrans(W2) ----------------
// blocks [0,8448): gather 2 rows each; [8448,12544): W1^T; [12544,16640): W2^T
__device__ __forceinline__ void wtrans_body(
    const float* __restrict__ in, _Float16* __restrict__ out,
    int K, int N, int e, int n0, int k0, float (*tile)[65]) {
  const float* src = in + (size_t)e * K * N;
  _Float16* dst = out + (size_t)e * K * N;
  int t = threadIdx.x;
  {
    int kk = t >> 2, nc = (t & 3) * 16;
    const float* p = src + (size_t)(k0 + kk) * N + n0 + nc;
#pragma unroll
    for (int j = 0; j < 4; ++j) {
      fvec4 v = *(const fvec4*)(p + j * 4);
      tile[kk][nc + j * 4 + 0] = v[0]; tile[kk][nc + j * 4 + 1] = v[1];
      tile[kk][nc + j * 4 + 2] = v[2]; tile[kk][nc + j * 4 + 3] = v[3];
    }
  }
  __syncthreads();
  {
    int nn = t >> 2, kb = (t & 3) * 16;
    f16x8 o0, o1;
#pragma unroll
    for (int j = 0; j < 8; ++j) o0[j] = (_Float16)tile[kb + j][nn];
#pragma unroll
    for (int j = 0; j < 8; ++j) o1[j] = (_Float16)tile[kb + 8 + j][nn];
    _Float16* q = dst + (size_t)(n0 + nn) * K + k0 + kb;
    *(f16x8*)q = o0;
    *((f16x8*)q + 1) = o1;
  }
}

__global__ __launch_bounds__(256) void aux_k(
    const float* __restrict__ x, const int* __restrict__ offs,
    const int* __restrict__ counts, const int* __restrict__ tok,
    _Float16* __restrict__ Xg,
    const float* __restrict__ W1, _Float16* __restrict__ W1f,
    const float* __restrict__ W2, _Float16* __restrict__ W2f) {
  __shared__ float tile[64][65];
  int b = blockIdx.x;
  if (b < 8448) {
    // gather: 2 rows per block, 128 threads each
    int row = b * 2 + (threadIdx.x >> 7);
    int tid = threadIdx.x & 127;
    if (row >= offs[4]) return;
    int e = 0;
    while (e < 3 && row >= offs[e + 1]) ++e;
    f16x8 o;
    if (row < offs[e] + counts[e]) {
      int t = tok[row];
      const float* src = x + (size_t)t * D_MODEL + tid * 8;
      fvec4 v0 = *(const fvec4*)src;
      fvec4 v1 = *(const fvec4*)(src + 4);
#pragma unroll
      for (int j = 0; j < 4; ++j) { o[j] = (_Float16)v0[j]; o[4 + j] = (_Float16)v1[j]; }
    } else {
#pragma unroll
      for (int j = 0; j < 8; ++j) o[j] = (_Float16)0.f;
    }
    *(f16x8*)(Xg + (size_t)row * D_MODEL + tid * 8) = o;
  } else if (b < 12544) {
    int bb = b - 8448;   // W1: K=1024, N=4096; 64(n) x 16(k) x 4(e)
    int n0 = (bb & 63) * 64, k0 = ((bb >> 6) & 15) * 64, e = bb >> 10;
    wtrans_body(W1, W1f, 1024, 4096, e, n0, k0, tile);
  } else {
    int bb = b - 12544;  // W2: K=4096, N=1024; 16(n) x 64(k) x 4(e)
    int n0 = (bb & 15) * 64, k0 = ((bb >> 4) & 63) * 64, e = bb >> 10;
    wtrans_body(W2, W2f, 4096, 1024, e, n0, k0, tile);
  }
}

// XOR-swizzled LDS fragment read (zero bank conflicts)
__device__ __forceinline__ f16x8 lds_frag(const char* base, int row, int kbyte) {
  return *(const f16x8*)(base + row * 128 + (kbyte ^ ((row & 7) << 4)));
}

// ============ GEMM1: 128x256 tile, K=1024, fast-gelu epilogue ============
__global__ __launch_bounds__(256, 2) void gemm1_k(
    const _Float16* __restrict__ A, const _Float16* __restrict__ B,
    const float* __restrict__ bias, const int* __restrict__ offs,
    const int* __restrict__ counts, _Float16* __restrict__ outH) {
  __shared__ char lds[49152];
  // nwg = 132*16 = 2112; bijective XCD swizzle: q=264
  int bid = blockIdx.x;
  int wg = (bid & 7) * 264 + (bid >> 3);
  int col = wg & 15, row = wg >> 4;       // col-fastest
  int rowBase = row * 128;
  if (rowBase >= offs[4]) return;
  int e = 0;
  while (e < 3 && rowBase >= offs[e + 1]) ++e;
  if (rowBase >= offs[e] + counts[e]) return;
  int colBase = col * 256;

  int tid = threadIdx.x, wid = tid >> 6, lane = tid & 63;
  int wr = wid >> 1, wc = wid & 1;
  int ln = lane & 15;
  int srow = lane >> 3;
  int kx = (lane & 7) ^ srow;
  const _Float16* Abase = A + (size_t)rowBase * 1024 + kx * 8;
  const _Float16* Bbase = B + (size_t)e * D_FF * 1024 + (size_t)colBase * 1024 + kx * 8;
  char* ldsA = lds;
  char* ldsB = lds + 16384;

  f32x4 acc[4][8];
  f32x4 zero = {0.f, 0.f, 0.f, 0.f};
#pragma unroll
  for (int m = 0; m < 4; ++m)
#pragma unroll
    for (int n = 0; n < 8; ++n) acc[m][n] = zero;

  for (int k0 = 0; k0 < 1024; k0 += 64) {
#pragma unroll
    for (int i = 0; i < 4; ++i) {
      int chunk = wid * 4 + i;
      gload_lds16(Abase + (size_t)(chunk * 8 + srow) * 1024 + k0, ldsA + chunk * 1024);
    }
#pragma unroll
    for (int i = 0; i < 8; ++i) {
      int chunk = wid * 8 + i;
      gload_lds16(Bbase + (size_t)(chunk * 8 + srow) * 1024 + k0, ldsB + chunk * 1024);
    }
    __syncthreads();
#pragma unroll
    for (int kk = 0; kk < 2; ++kk) {
      int kbyte = kk * 64 + (lane >> 4) * 16;
      f16x8 af[4], bf[8];
#pragma unroll
      for (int m = 0; m < 4; ++m)
        af[m] = lds_frag(ldsA, wr * 64 + m * 16 + ln, kbyte);
#pragma unroll
      for (int n = 0; n < 8; ++n)
        bf[n] = lds_frag(ldsB, wc * 128 + n * 16 + ln, kbyte);
#pragma unroll
      for (int m = 0; m < 4; ++m)
#pragma unroll
        for (int n = 0; n < 8; ++n)
          acc[m][n] = __builtin_amdgcn_mfma_f32_16x16x32_f16(af[m], bf[n], acc[m][n], 0, 0, 0);
    }
    __syncthreads();
  }

  int col0 = colBase + wc * 128 + ln;
  float bv[8];
#pragma unroll
  for (int n = 0; n < 8; ++n) bv[n] = bias[(size_t)e * D_FF + col0 + n * 16];
#pragma unroll
  for (int m = 0; m < 4; ++m) {
    int rbase = rowBase + wr * 64 + m * 16 + (lane >> 4) * 4;
#pragma unroll
    for (int j = 0; j < 4; ++j) {
      size_t ro = (size_t)(rbase + j) * D_FF;
#pragma unroll
      for (int n = 0; n < 8; ++n) {
        float v = fast_gelu(acc[m][n][j] + bv[n]);
        outH[ro + col0 + n * 16] = (_Float16)v;
      }
    }
  }
}

// ============ GEMM2: 128x128 tile, split-K=2, weighted-atomic epilogue ============
// A: H [CAP_ROWS][4096]; B: W2^T [4][1024][4096]; out: atomicAdd into out[tok][d].
__global__ __launch_bounds__(256, 3) void gemm2_k(
    const _Float16* __restrict__ A, const _Float16* __restrict__ B,
    const float* __restrict__ bias, const int* __restrict__ offs,
    const int* __restrict__ counts, const int* __restrict__ tok,
    const float* __restrict__ wgt, float* __restrict__ outF) {
  __shared__ char lds[32768];
  // nwg = 132*8*2 = 2112; bijective XCD swizzle: q=264
  int bid = blockIdx.x;
  int wg = (bid & 7) * 264 + (bid >> 3);
  int col = wg & 7, kz = (wg >> 3) & 1, row = wg >> 4;  // col-fastest within (row,kz)
  int rowBase = row * 128;
  if (rowBase >= offs[4]) return;
  int e = 0;
  while (e < 3 && rowBase >= offs[e + 1]) ++e;
  int eoff = offs[e], cnt = counts[e];
  if (rowBase >= eoff + cnt) return;
  int colBase = col * 128;
  int kbase = kz * 2048;

  int tid = threadIdx.x, wid = tid >> 6, lane = tid & 63;
  int wr = wid >> 1, wc = wid & 1;
  int ln = lane & 15;
  int srow = lane >> 3;
  int kx = (lane & 7) ^ srow;
  const _Float16* Abase = A + (size_t)rowBase * 4096 + kx * 8;
  const _Float16* Bbase = B + (size_t)e * D_MODEL * 4096 + (size_t)colBase * 4096 + kx * 8;
  char* ldsA = lds;
  char* ldsB = lds + 16384;

  f32x4 acc[4][4];
  f32x4 zero = {0.f, 0.f, 0.f, 0.f};
#pragma unroll
  for (int m = 0; m < 4; ++m)
#pragma unroll
    for (int n = 0; n < 4; ++n) acc[m][n] = zero;

  for (int k0 = kbase; k0 < kbase + 2048; k0 += 64) {
#pragma unroll
    for (int i = 0; i < 4; ++i) {
      int chunk = wid * 4 + i;               // 0..15 -> 128 rows
      gload_lds16(Abase + (size_t)(chunk * 8 + srow) * 4096 + k0, ldsA + chunk * 1024);
      gload_lds16(Bbase + (size_t)(chunk * 8 + srow) * 4096 + k0, ldsB + chunk * 1024);
    }
    __syncthreads();
#pragma unroll
    for (int kk = 0; kk < 2; ++kk) {
      int kbyte = kk * 64 + (lane >> 4) * 16;
      f16x8 af[4], bf[4];
#pragma unroll
      for (int m = 0; m < 4; ++m)
        af[m] = lds_frag(ldsA, wr * 64 + m * 16 + ln, kbyte);
#pragma unroll
      for (int n = 0; n < 4; ++n)
        bf[n] = lds_frag(ldsB, wc * 64 + n * 16 + ln, kbyte);
#pragma unroll
      for (int m = 0; m < 4; ++m)
#pragma unroll
        for (int n = 0; n < 4; ++n)
          acc[m][n] = __builtin_amdgcn_mfma_f32_16x16x32_f16(af[m], bf[n], acc[m][n], 0, 0, 0);
    }
    __syncthreads();
  }

  int col0 = colBase + wc * 64 + ln;
  float bv[4];
#pragma unroll
  for (int n = 0; n < 4; ++n)
    bv[n] = (kz == 0) ? bias[(size_t)e * D_MODEL + col0 + n * 16] : 0.f;
#pragma unroll
  for (int m = 0; m < 4; ++m) {
    int rbase = rowBase + wr * 64 + m * 16 + (lane >> 4) * 4;
#pragma unroll
    for (int j = 0; j < 4; ++j) {
      int grow = rbase + j;
      if (grow - eoff < cnt) {
        int t = tok[grow];
        float w = wgt[grow];
        size_t o = (size_t)t * D_MODEL + col0;
#pragma unroll
        for (int n = 0; n < 4; ++n)
          atomicAdd(&outF[o + n * 16], w * (acc[m][n][j] + bv[n]));
      }
    }
  }
}

extern "C" void kernel_launch(void* const* d_in, const int* in_sizes, int n_in,
                              void* d_out, int out_size, void* d_ws, size_t ws_size,
                              hipStream_t stream) {
  const float* x  = (const float*)d_in[0];
  const float* Wr = (const float*)d_in[1];
  const float* br = (const float*)d_in[2];
  const float* W1 = (const float*)d_in[3];
  const float* b1 = (const float*)d_in[4];
  const float* W2 = (const float*)d_in[5];
  const float* b2 = (const float*)d_in[6];
  float* out = (float*)d_out;
  char* ws = (char*)d_ws;
  if (ws_size < WS_NEED) return;

  _Float16* W1f = (_Float16*)(ws + OFF_W1);
  _Float16* W2f = (_Float16*)(ws + OFF_W2);
  _Float16* Xg  = (_Float16*)(ws + OFF_XG);
  _Float16* H   = (_Float16*)(ws + OFF_H);
  int*   counts = (int*)(ws + OFF_CNT);
  int*   cursor = (int*)(ws + OFF_CUR);
  int*   offs   = (int*)(ws + OFF_OFS);
  int*   tok    = (int*)(ws + OFF_TOK);
  float* wgt    = (float*)(ws + OFF_WGT);
  int*   e12    = (int*)(ws + OFF_E12);
  float* w12    = (float*)(ws + OFF_W12);

  hipMemsetAsync(counts, 0, 16, stream);
  hipMemsetAsync(d_out, 0, (size_t)out_size * sizeof(float), stream);

  router_k<<<NTOK / 4, 256, 0, stream>>>(x, Wr, br, counts, e12, w12);
  prefix_k<<<1, 64, 0, stream>>>(counts, offs, cursor);
  lists_k<<<NTOK / 256, 256, 0, stream>>>(e12, w12, cursor, tok, wgt);
  aux_k<<<16640, 256, 0, stream>>>(x, offs, counts, tok, Xg, W1, W1f, W2, W2f);

  gemm1_k<<<NRB * 16, 256, 0, stream>>>(Xg, W1f, b1, offs, counts, H);
  gemm2_k<<<NRB * 16, 256, 0, stream>>>(H, W2f, b2, offs, counts, tok, wgt, out);
}